// Round 7
// baseline (476.106 us; speedup 1.0000x reference)
//
#include <hip/hip_runtime.h>
#include <math.h>

#define BB 256
#define TT 512
#define LL 40
#define ED 8
#define NC 22
#define HH 64
#define BLK 320   // wave0 = eta+PK; waves1-4 (256 lanes) = dots+GRU, 4 lanes/unit

#define L2E 1.4426950408889634f
#define S2E 2.8853900817779268f   // 2*log2(e)

__device__ __forceinline__ float fast_rcp(float x)  { return __builtin_amdgcn_rcpf(x); }
__device__ __forceinline__ float fast_exp2(float x) { return __builtin_amdgcn_exp2f(x); }

__device__ __forceinline__ float dpp_add_xor1(float x) {   // quad_perm [1,0,3,2]
    int v = __builtin_amdgcn_update_dpp(0, __float_as_int(x), 0xB1, 0xF, 0xF, true);
    return x + __int_as_float(v);
}
__device__ __forceinline__ float dpp_add_xor2(float x) {   // quad_perm [2,3,0,1]
    int v = __builtin_amdgcn_update_dpp(0, __float_as_int(x), 0x4E, 0xF, 0xF, true);
    return x + __int_as_float(v);
}
__device__ __forceinline__ float quad_sum(float x) { return dpp_add_xor2(dpp_add_xor1(x)); }

// sum over each 16-lane row (xor1, xor2, half-mirror, mirror — all row-local DPP)
__device__ __forceinline__ float dpp_reduce16(float x) {
    int v;
    v = __builtin_amdgcn_update_dpp(0, __float_as_int(x), 0xB1, 0xF, 0xF, true);  x += __int_as_float(v);
    v = __builtin_amdgcn_update_dpp(0, __float_as_int(x), 0x4E, 0xF, 0xF, true);  x += __int_as_float(v);
    v = __builtin_amdgcn_update_dpp(0, __float_as_int(x), 0x141, 0xF, 0xF, true); x += __int_as_float(v);
    v = __builtin_amdgcn_update_dpp(0, __float_as_int(x), 0x140, 0xF, 0xF, true); x += __int_as_float(v);
    return x;
}

__global__ __launch_bounds__(BLK, 1) void scan_kernel(
    const float* __restrict__ cont, const int* __restrict__ cat,
    const float* __restrict__ lb, const int* __restrict__ mask,
    const float* __restrict__ dvec, const float* __restrict__ td,
    const float* __restrict__ emb,
    const float* __restrict__ W_ih, const float* __restrict__ W_hh,
    const float* __restrict__ b_ih, const float* __restrict__ b_hh,
    const float* __restrict__ W_out, const float* __restrict__ b_out,
    float* __restrict__ out)
{
    const int b   = blockIdx.x;
    const int tid = threadIdx.x;

    // feat rows 128B-aligned (32 floats): [0..7]=emb-sum, [8..29]=cont, [30]=0(vfb excluded from dots), [31]=0
    __shared__ __align__(128) float  feat[TT * 32];   // 64 KB
    __shared__ __align__(16)  float4 sc[TT];          // {d*L2E, (td24-d)*L2E, maskf, lb}
    __shared__ float  cclA[TT];
    // h layout for bank-conflict-free quad reads: h[0..31] at hbuf[0..31],
    // h[32..63] at hbuf[36..67] (byte offset 144 -> bank-group phase +4)
    __shared__ __align__(128) float hbuf[72];
    __shared__ __align__(16) float out_lds[TT];
    __shared__ float vfb_lds;
    __shared__ float kb_lds;

    const size_t bT    = (size_t)b * TT;
    const int*   catb  = cat  + bT * LL;
    const float* contb = cont + bT * NC;

    // ---- roles ----
    const bool isDot = (tid >= 64);
    const int  Ld = tid - 64;        // 0..255
    const int  j  = Ld >> 2;         // hidden unit (0..63)
    const int  q  = Ld & 3;          // feature quarter: f in [24q, 24q+24)
    const int  ei = tid & 15, ej = tid >> 4;   // wave0 eta layout

    // ---- per-lane weights (prescaled for exp2-based sigmoid/tanh) ----
    float wr_[24], wz_[24], wn_[24];
    float br = 0.f, bz = 0.f, bnx = 0.f, bnh = 0.f;
    float w30r = 0.f, w30z = 0.f, w30n = 0.f;
    float wo0 = 0.f, wo1 = 0.f, wo2 = 0.f, wo3 = 0.f;
    if (isDot) {
        #pragma unroll
        for (int m = 0; m < 24; ++m) {
            const int f = 24 * q + m;
            float a, c, d;
            if (f < 30)      { a = W_ih[j*31+f]; c = W_ih[(j+64)*31+f]; d = W_ih[(j+128)*31+f]; }
            else if (f < 32) { a = 0.f; c = 0.f; d = 0.f; }
            else             { a = W_hh[j*64+f-32]; c = W_hh[(j+64)*64+f-32]; d = W_hh[(j+128)*64+f-32]; }
            wr_[m] = a * L2E;
            wz_[m] = c * L2E;
            wn_[m] = d * S2E;
        }
        #pragma unroll
        for (int m = 0; m < 24; ++m) {
            asm volatile("" : "+v"(wr_[m]));
            asm volatile("" : "+v"(wz_[m]));
            asm volatile("" : "+v"(wn_[m]));
        }
        br   = (b_ih[j]      + b_hh[j])      * L2E;
        bz   = (b_ih[j + 64] + b_hh[j + 64]) * L2E;
        bnx  = b_ih[j + 128] * S2E;
        bnh  = b_hh[j + 128] * S2E;
        w30r = W_ih[j*31 + 30]        * L2E;
        w30z = W_ih[(j+64)*31 + 30]   * L2E;
        w30n = W_ih[(j+128)*31 + 30]  * S2E;
    } else {
        wo0 = W_out[ej * 64 + 4*ei + 0] * L2E;
        wo1 = W_out[ej * 64 + 4*ei + 1] * L2E;
        wo2 = W_out[ej * 64 + 4*ei + 2] * L2E;
        wo3 = W_out[ej * 64 + 4*ei + 3] * L2E;
    }
    const float boL0 = b_out[0] * L2E, boL1 = b_out[1] * L2E;
    const float boL2 = b_out[2] * L2E, boL3 = b_out[3] * L2E;

    // ---- prologue: fused xbuild — stage everything into LDS ----
    for (int i = tid; i < TT * NC; i += BLK) {          // cont -> feat[.][8..29]
        int r = i / NC, c = i - r * NC;
        feat[r * 32 + 8 + c] = contb[i];
    }
    for (int i = tid; i < TT; i += BLK) {               // pads
        feat[i * 32 + 30] = 0.f;
        feat[i * 32 + 31] = 0.f;
    }
    for (int i = tid; i < TT * 8; i += BLK) {           // embedding gather -> feat[.][0..7]
        int r = i >> 3, e = i & 7;
        const int* cp = catb + r * LL;
        float acc = 0.f;
        #pragma unroll 8
        for (int l = 0; l < LL; ++l) acc += emb[cp[l] * ED + e];
        feat[r * 32 + e] = acc;
    }
    for (int i = tid; i < TT; i += BLK) {               // per-step scalars (exp2-prescaled)
        float d   = dvec[bT + i];
        float t24 = td[bT + i] * 24.0f;
        sc[i] = make_float4(d * L2E, (t24 - d) * L2E, (float)mask[bT + i], lb[bT + i]);
    }
    if (tid < 72) hbuf[tid] = 0.f;
    if (tid == 0) vfb_lds = 0.f;
    if (tid < 64) {                                     // Kb via ballot over cat[b][0][:]
        int cv = (tid < LL) ? catb[tid] : 0;
        unsigned long long bal = __ballot(tid < LL && cv == 5);
        float g   = (float)__popcll(bal) * 0.15f + 0.85f;
        float age = contb[2]  * 16.936469f + 58.239251f;
        float wgt = contb[21] * 30.519849f + 87.5752f;
        if (tid == 0) kb_lds = (140.0f - age) * wgt * g / 72.0f;
    }
    __syncthreads();
    {
        const float Kb = kb_lds;
        for (int i = tid; i < TT; i += BLK)
            cclA[i] = Kb * fast_rcp(fmaf(contb[i * NC + 11], 1.418099f, 1.314668f));
    }
    __syncthreads();

    // ---- persistent state ----
    float hreg = 0.f;                      // dot lanes: h_j (replicated in quad)
    float Cc = 0.f, Dc = 0.f;              // wave0 PK state
    float sr = 0.f, sz = 0.f, snx = 0.f, snh = 0.f;
    float4 svc = make_float4(0.f, 0.f, 0.f, 0.f);
    float  ccv = 0.f;

    const float4* hA4 = (const float4*)hbuf;
    const float4* hB4 = (const float4*)(hbuf + 36);

    auto do_dots = [&](int t) {
        const float4* f4t = (const float4*)(feat + t * 32);
        float ra = 0.f, za = 0.f, nxa = 0.f, nha = 0.f;
        #pragma unroll
        for (int k = 0; k < 6; ++k) {
            const int idx = 6 * q + k;
            const float4* pH = (idx < 16) ? (hA4 + (idx - 8)) : (hB4 + (idx - 16));
            const float4* p  = (idx < 8) ? (f4t + idx) : pH;
            const float4 uv = *p;
            ra = fmaf(uv.x, wr_[4*k+0], ra);
            ra = fmaf(uv.y, wr_[4*k+1], ra);
            ra = fmaf(uv.z, wr_[4*k+2], ra);
            ra = fmaf(uv.w, wr_[4*k+3], ra);
            za = fmaf(uv.x, wz_[4*k+0], za);
            za = fmaf(uv.y, wz_[4*k+1], za);
            za = fmaf(uv.z, wz_[4*k+2], za);
            za = fmaf(uv.w, wz_[4*k+3], za);
            if (idx < 8) {
                nxa = fmaf(uv.x, wn_[4*k+0], nxa);
                nxa = fmaf(uv.y, wn_[4*k+1], nxa);
                nxa = fmaf(uv.z, wn_[4*k+2], nxa);
                nxa = fmaf(uv.w, wn_[4*k+3], nxa);
            } else {
                nha = fmaf(uv.x, wn_[4*k+0], nha);
                nha = fmaf(uv.y, wn_[4*k+1], nha);
                nha = fmaf(uv.z, wn_[4*k+2], nha);
                nha = fmaf(uv.w, wn_[4*k+3], nha);
            }
        }
        sr  = quad_sum(ra);
        sz  = quad_sum(za);
        snx = quad_sum(nxa);
        snh = quad_sum(nha);
    };

    if (isDot) do_dots(0);

    for (int t = 0; t < TT; ++t) {
        // ---- alpha: dot lanes GRU(t); wave0 prefetches scalars ----
        if (isDot) {
            const float vfb = vfb_lds;
            float prer = sr + br + vfb * w30r;
            float prez = sz + bz + vfb * w30z;
            float r = fast_rcp(1.0f + fast_exp2(-prer));
            float z = fast_rcp(1.0f + fast_exp2(-prez));
            float yp = snx + bnx + vfb * w30n + r * (snh + bnh);
            float n = 1.0f - 2.0f * fast_rcp(fast_exp2(yp) + 1.0f);
            hreg = fmaf(z, hreg - n, n);
            if (q == 0) hbuf[(j < 32) ? j : (36 + j - 32)] = hreg;
        } else {
            svc = sc[t];
            ccv = cclA[t];
        }
        __syncthreads();   // B: h(t) visible

        // ---- beta: dots(t+1)  ||  wave0 eta+PK(t) ----
        if (isDot) {
            if (t + 1 < TT) do_dots(t + 1);
        } else {
            const float4 hv = (ei < 8) ? hA4[ei] : hB4[ei - 8];
            float p = hv.x * wo0;
            p = fmaf(hv.y, wo1, p);
            p = fmaf(hv.z, wo2, p);
            p = fmaf(hv.w, wo3, p);
            p = dpp_reduce16(p);
            const float e0 = __int_as_float(__builtin_amdgcn_readlane(__float_as_int(p), 0));
            const float e1 = __int_as_float(__builtin_amdgcn_readlane(__float_as_int(p), 16));
            const float e2 = __int_as_float(__builtin_amdgcn_readlane(__float_as_int(p), 32));
            const float e3 = __int_as_float(__builtin_amdgcn_readlane(__float_as_int(p), 48));

            float E1 = fast_exp2(e0 + boL0);
            float E2 = fast_exp2(e1 + boL1);
            float E3 = fast_exp2(e2 + boL2);
            float E4 = fast_exp2(e3 + boL3);
            float v1  = 33.1f * E1;
            float rv1 = fast_rcp(v1);
            float k1  = 0.0396f * ccv * E2;
            float rrr = 1000.0f * rv1;
            float v2  = 48.3f * E4;
            float R   = (-6.99f / 48.3f) * E3;
            float k2  = R * v2;
            float qq  = k1 - k2 - R * v1;
            float disc = fmaf(qq, qq, 4.0f * k1 * R * v1);
            float delta = __builtin_amdgcn_sqrtf(disc) * rv1;
            float sgm  = (k2 - k1 + R * v1) * rv1;
            float lam1 = (sgm - delta) * 0.5f;
            float lam2 = (sgm + delta) * 0.5f;
            float kv  = k2 * rv1;
            float rkv = fast_rcp(kv);
            float C1  = rrr * kv * fast_rcp(lam1 * delta);
            float C2  = -rrr * kv * fast_rcp(lam2 * delta);
            float C3  = -(lam1 - R) * rkv;
            float C4  = -(lam2 - R) * rkv;
            float Cn  = fmaf(Cc + C1, fast_exp2(lam1 * svc.x), -C1) * fast_exp2(lam1 * svc.y);
            float Dn  = fmaf(Dc + C2, fast_exp2(lam2 * svc.x), -C2) * fast_exp2(lam2 * svc.y);
            float An  = fmaf(Cn, C3, Dn * C4);
            Cc = Cn; Dc = Dn;
            if (tid == 0) {
                out_lds[t] = An;
                vfb_lds = fmaf(An, 1.0f - svc.z, svc.w * svc.z);   // vfb(t+1)
            }
        }
        __syncthreads();   // A: vfb(t+1) visible; h reads done
    }

    if (tid < TT / 4) ((float4*)(out + bT))[tid] = ((const float4*)out_lds)[tid];
}

extern "C" void kernel_launch(void* const* d_in, const int* in_sizes, int n_in,
                              void* d_out, int out_size, void* d_ws, size_t ws_size,
                              hipStream_t stream) {
    const float* cont  = (const float*)d_in[0];
    const int*   cat   = (const int*)  d_in[1];
    const float* lb    = (const float*)d_in[2];
    const int*   mask  = (const int*)  d_in[3];
    const float* dvec  = (const float*)d_in[4];
    const float* td    = (const float*)d_in[5];
    const float* emb   = (const float*)d_in[6];
    const float* W_ih  = (const float*)d_in[7];
    const float* W_hh  = (const float*)d_in[8];
    const float* b_ih  = (const float*)d_in[9];
    const float* b_hh  = (const float*)d_in[10];
    const float* W_out = (const float*)d_in[11];
    const float* b_out = (const float*)d_in[12];
    float* out = (float*)d_out;

    hipLaunchKernelGGL(scan_kernel, dim3(BB), dim3(BLK), 0, stream,
                       cont, cat, lb, mask, dvec, td, emb, W_ih, W_hh, b_ih, b_hh,
                       W_out, b_out, out);
}

// Round 8
// 425.481 us; speedup vs baseline: 1.1190x; 1.1190x over previous
//
#include <hip/hip_runtime.h>
#include <math.h>

#define BB 256
#define TT 512
#define LL 40
#define ED 8
#define NC 22
#define HH 64
#define BLK 576   // lanes 0-511: dots+GRU (8 lanes/unit); wave8 (512-575): eta+PK

#define L2E 1.4426950408889634f
#define S2E 2.8853900817779268f   // 2*log2(e)

__device__ __forceinline__ float fast_rcp(float x)  { return __builtin_amdgcn_rcpf(x); }
__device__ __forceinline__ float fast_exp2(float x) { return __builtin_amdgcn_exp2f(x); }

__device__ __forceinline__ float dpp_add_xor1(float x) {   // quad_perm [1,0,3,2]
    int v = __builtin_amdgcn_update_dpp(0, __float_as_int(x), 0xB1, 0xF, 0xF, true);
    return x + __int_as_float(v);
}
__device__ __forceinline__ float dpp_add_xor2(float x) {   // quad_perm [2,3,0,1]
    int v = __builtin_amdgcn_update_dpp(0, __float_as_int(x), 0x4E, 0xF, 0xF, true);
    return x + __int_as_float(v);
}
__device__ __forceinline__ float dpp_add_mirror8(float x) { // row_half_mirror (xor7 in 8-group)
    int v = __builtin_amdgcn_update_dpp(0, __float_as_int(x), 0x141, 0xF, 0xF, true);
    return x + __int_as_float(v);
}
// full sum over each 8-lane octant group (result in all 8 lanes)
__device__ __forceinline__ float red8(float x) {
    return dpp_add_mirror8(dpp_add_xor2(dpp_add_xor1(x)));
}
// sum over each 16-lane row
__device__ __forceinline__ float dpp_reduce16(float x) {
    int v;
    v = __builtin_amdgcn_update_dpp(0, __float_as_int(x), 0xB1, 0xF, 0xF, true);  x += __int_as_float(v);
    v = __builtin_amdgcn_update_dpp(0, __float_as_int(x), 0x4E, 0xF, 0xF, true);  x += __int_as_float(v);
    v = __builtin_amdgcn_update_dpp(0, __float_as_int(x), 0x141, 0xF, 0xF, true); x += __int_as_float(v);
    v = __builtin_amdgcn_update_dpp(0, __float_as_int(x), 0x140, 0xF, 0xF, true); x += __int_as_float(v);
    return x;
}

__global__ __launch_bounds__(BLK, 3) void scan_kernel(
    const float* __restrict__ cont, const int* __restrict__ cat,
    const float* __restrict__ lb, const int* __restrict__ mask,
    const float* __restrict__ dvec, const float* __restrict__ td,
    const float* __restrict__ emb,
    const float* __restrict__ W_ih, const float* __restrict__ W_hh,
    const float* __restrict__ b_ih, const float* __restrict__ b_hh,
    const float* __restrict__ W_out, const float* __restrict__ b_out,
    float* __restrict__ out)
{
    const int b   = blockIdx.x;
    const int tid = threadIdx.x;

    // feat rows: 32 floats = 8 float4s: [0..7]=emb-sum, [8..29]=cont, [30]=0, [31]=0
    __shared__ __align__(128) float  feat[TT * 32];   // 64 KB
    __shared__ __align__(16)  float4 sc[TT];          // {d*L2E, (td24-d)*L2E, maskf, lb}
    __shared__ float  cclA[TT];
    __shared__ __align__(16)  float  hbuf[HH];        // h(t), plain layout
    __shared__ __align__(16)  float  out_lds[TT];
    __shared__ float vfb_lds;
    __shared__ float kb_lds;

    const size_t bT    = (size_t)b * TT;
    const int*   catb  = cat  + bT * LL;
    const float* contb = cont + bT * NC;

    // ---- roles ----
    const bool isDot = (tid < 512);
    const int  j  = tid >> 3;        // hidden unit (0..63)        [dot lanes]
    const int  s  = tid & 7;         // octant: float4 slots s, s+8(h), s+16(h)
    const int  l8 = tid - 512;       // wave8 lane (0..63)
    const int  ei = l8 & 15, ej = l8 >> 4;

    // ---- per-lane weights: 12 per gate (x-quad, h-lo-quad, h-hi-quad), prescaled ----
    float wr_[12], wz_[12], wn_[12];
    float br = 0.f, bz = 0.f, bnx = 0.f, bnh = 0.f;
    float w30r = 0.f, w30z = 0.f, w30n = 0.f;
    float wo0 = 0.f, wo1 = 0.f, wo2 = 0.f, wo3 = 0.f;
    if (isDot) {
        const int cx0 = 4 * s;
        #pragma unroll
        for (int m = 0; m < 4; ++m) {
            const int cx = cx0 + m;
            const float xr = (cx < 30) ? W_ih[j * 31 + cx]         : 0.f;
            const float xz = (cx < 30) ? W_ih[(j + 64) * 31 + cx]  : 0.f;
            const float xn = (cx < 30) ? W_ih[(j + 128) * 31 + cx] : 0.f;
            wr_[m]     = xr * L2E;
            wz_[m]     = xz * L2E;
            wn_[m]     = xn * S2E;
            wr_[4 + m] = W_hh[j * 64 + cx]              * L2E;
            wz_[4 + m] = W_hh[(j + 64) * 64 + cx]       * L2E;
            wn_[4 + m] = W_hh[(j + 128) * 64 + cx]      * S2E;
            wr_[8 + m] = W_hh[j * 64 + 32 + cx]         * L2E;
            wz_[8 + m] = W_hh[(j + 64) * 64 + 32 + cx]  * L2E;
            wn_[8 + m] = W_hh[(j + 128) * 64 + 32 + cx] * S2E;
        }
        #pragma unroll
        for (int m = 0; m < 12; ++m) {
            asm volatile("" : "+v"(wr_[m]));
            asm volatile("" : "+v"(wz_[m]));
            asm volatile("" : "+v"(wn_[m]));
        }
        br   = (b_ih[j]      + b_hh[j])      * L2E;
        bz   = (b_ih[j + 64] + b_hh[j + 64]) * L2E;
        bnx  = b_ih[j + 128] * S2E;
        bnh  = b_hh[j + 128] * S2E;
        w30r = W_ih[j * 31 + 30]         * L2E;
        w30z = W_ih[(j + 64) * 31 + 30]  * L2E;
        w30n = W_ih[(j + 128) * 31 + 30] * S2E;
    } else {
        wo0 = W_out[ej * 64 + 4 * ei + 0] * L2E;
        wo1 = W_out[ej * 64 + 4 * ei + 1] * L2E;
        wo2 = W_out[ej * 64 + 4 * ei + 2] * L2E;
        wo3 = W_out[ej * 64 + 4 * ei + 3] * L2E;
    }
    const float boL0 = b_out[0] * L2E, boL1 = b_out[1] * L2E;
    const float boL2 = b_out[2] * L2E, boL3 = b_out[3] * L2E;

    // ---- prologue: stage everything into LDS ----
    for (int i = tid; i < TT * NC; i += BLK) {          // cont -> feat[.][8..29]
        int r = i / NC, c = i - r * NC;
        feat[r * 32 + 8 + c] = contb[i];
    }
    for (int i = tid; i < TT; i += BLK) {               // pads (vfb slot excluded from dots)
        feat[i * 32 + 30] = 0.f;
        feat[i * 32 + 31] = 0.f;
    }
    for (int i = tid; i < TT * 2; i += BLK) {           // emb gather, float4-vectorized
        int r = i >> 1, qd = i & 1;                     // qd = which half of 8 emb dims
        const int* cp = catb + r * LL;
        float4 acc = make_float4(0.f, 0.f, 0.f, 0.f);
        #pragma unroll 8
        for (int l = 0; l < LL; ++l) {
            const float4 ev = *((const float4*)(emb + cp[l] * ED) + qd);
            acc.x += ev.x; acc.y += ev.y; acc.z += ev.z; acc.w += ev.w;
        }
        ((float4*)feat)[r * 8 + qd] = acc;
    }
    for (int i = tid; i < TT; i += BLK) {               // per-step scalars (exp2-prescaled)
        float d   = dvec[bT + i];
        float t24 = td[bT + i] * 24.0f;
        sc[i] = make_float4(d * L2E, (t24 - d) * L2E, (float)mask[bT + i], lb[bT + i]);
    }
    if (tid < HH) hbuf[tid] = 0.f;
    if (tid == 0) vfb_lds = 0.f;
    if (tid < 64) {                                     // Kb via ballot over cat[b][0][:]
        int cv = (tid < LL) ? catb[tid] : 0;
        unsigned long long bal = __ballot(tid < LL && cv == 5);
        float g   = (float)__popcll(bal) * 0.15f + 0.85f;
        float age = contb[2]  * 16.936469f + 58.239251f;
        float wgt = contb[21] * 30.519849f + 87.5752f;
        if (tid == 0) kb_lds = (140.0f - age) * wgt * g / 72.0f;
    }
    __syncthreads();
    {
        const float Kb = kb_lds;
        for (int i = tid; i < TT; i += BLK)
            cclA[i] = Kb * fast_rcp(fmaf(contb[i * NC + 11], 1.418099f, 1.314668f));
    }
    __syncthreads();

    // ---- persistent state ----
    float hreg = 0.f;                      // dot lanes: h_j (replicated in octant)
    float Cc = 0.f, Dc = 0.f;              // wave8 PK state
    float sr = 0.f, sz = 0.f, snx = 0.f, snh = 0.f;
    float4 svc = make_float4(0.f, 0.f, 0.f, 0.f);
    float  ccv = 0.f;

    const float4* hbuf4 = (const float4*)hbuf;

    // dots for step t: 3 conflict-free LDS float4 reads + 36 FMA + 4 octant reduces
    auto do_dots = [&](int t) {
        const float4 u0 = ((const float4*)(feat + t * 32))[s];   // x dims 4s..4s+3
        const float4 u1 = hbuf4[s];                              // h dims 4s..4s+3
        const float4 u2 = hbuf4[s + 8];                          // h dims 32+4s..
        float ra, za, nxa, nha;
        ra  = u0.x * wr_[0];
        ra  = fmaf(u0.y, wr_[1],  ra);
        ra  = fmaf(u0.z, wr_[2],  ra);
        ra  = fmaf(u0.w, wr_[3],  ra);
        ra  = fmaf(u1.x, wr_[4],  ra);
        ra  = fmaf(u1.y, wr_[5],  ra);
        ra  = fmaf(u1.z, wr_[6],  ra);
        ra  = fmaf(u1.w, wr_[7],  ra);
        ra  = fmaf(u2.x, wr_[8],  ra);
        ra  = fmaf(u2.y, wr_[9],  ra);
        ra  = fmaf(u2.z, wr_[10], ra);
        ra  = fmaf(u2.w, wr_[11], ra);
        za  = u0.x * wz_[0];
        za  = fmaf(u0.y, wz_[1],  za);
        za  = fmaf(u0.z, wz_[2],  za);
        za  = fmaf(u0.w, wz_[3],  za);
        za  = fmaf(u1.x, wz_[4],  za);
        za  = fmaf(u1.y, wz_[5],  za);
        za  = fmaf(u1.z, wz_[6],  za);
        za  = fmaf(u1.w, wz_[7],  za);
        za  = fmaf(u2.x, wz_[8],  za);
        za  = fmaf(u2.y, wz_[9],  za);
        za  = fmaf(u2.z, wz_[10], za);
        za  = fmaf(u2.w, wz_[11], za);
        nxa = u0.x * wn_[0];
        nxa = fmaf(u0.y, wn_[1],  nxa);
        nxa = fmaf(u0.z, wn_[2],  nxa);
        nxa = fmaf(u0.w, wn_[3],  nxa);
        nha = u1.x * wn_[4];
        nha = fmaf(u1.y, wn_[5],  nha);
        nha = fmaf(u1.z, wn_[6],  nha);
        nha = fmaf(u1.w, wn_[7],  nha);
        nha = fmaf(u2.x, wn_[8],  nha);
        nha = fmaf(u2.y, wn_[9],  nha);
        nha = fmaf(u2.z, wn_[10], nha);
        nha = fmaf(u2.w, wn_[11], nha);
        sr  = red8(ra);
        sz  = red8(za);
        snx = red8(nxa);
        snh = red8(nha);
    };

    if (isDot) do_dots(0);

    for (int t = 0; t < TT; ++t) {
        // ---- alpha: dot lanes GRU(t); wave8 prefetches scalars ----
        if (isDot) {
            const float vfb = vfb_lds;
            float prer = sr + br + vfb * w30r;
            float prez = sz + bz + vfb * w30z;
            float r = fast_rcp(1.0f + fast_exp2(-prer));
            float z = fast_rcp(1.0f + fast_exp2(-prez));
            float yp = snx + bnx + vfb * w30n + r * (snh + bnh);
            float n = 1.0f - 2.0f * fast_rcp(fast_exp2(yp) + 1.0f);
            hreg = fmaf(z, hreg - n, n);
            if (s == 0) hbuf[j] = hreg;
        } else {
            svc = sc[t];
            ccv = cclA[t];
        }
        __syncthreads();   // B: h(t) visible

        // ---- beta: dot lanes dots(t+1)  ||  wave8 eta+PK(t) ----
        if (isDot) {
            if (t + 1 < TT) do_dots(t + 1);
        } else {
            const float4 hv = hbuf4[ei];
            float p = hv.x * wo0;
            p = fmaf(hv.y, wo1, p);
            p = fmaf(hv.z, wo2, p);
            p = fmaf(hv.w, wo3, p);
            p = dpp_reduce16(p);
            const float e0 = __int_as_float(__builtin_amdgcn_readlane(__float_as_int(p), 0));
            const float e1 = __int_as_float(__builtin_amdgcn_readlane(__float_as_int(p), 16));
            const float e2 = __int_as_float(__builtin_amdgcn_readlane(__float_as_int(p), 32));
            const float e3 = __int_as_float(__builtin_amdgcn_readlane(__float_as_int(p), 48));

            float E1 = fast_exp2(e0 + boL0);
            float E2 = fast_exp2(e1 + boL1);
            float E3 = fast_exp2(e2 + boL2);
            float E4 = fast_exp2(e3 + boL3);
            float v1  = 33.1f * E1;
            float rv1 = fast_rcp(v1);
            float k1  = 0.0396f * ccv * E2;
            float rrr = 1000.0f * rv1;
            float v2  = 48.3f * E4;
            float R   = (-6.99f / 48.3f) * E3;
            float k2  = R * v2;
            float qq  = k1 - k2 - R * v1;
            float disc = fmaf(qq, qq, 4.0f * k1 * R * v1);
            float delta = __builtin_amdgcn_sqrtf(disc) * rv1;
            float sgm  = (k2 - k1 + R * v1) * rv1;
            float lam1 = (sgm - delta) * 0.5f;
            float lam2 = (sgm + delta) * 0.5f;
            float kv  = k2 * rv1;
            float rkv = fast_rcp(kv);
            float C1  = rrr * kv * fast_rcp(lam1 * delta);
            float C2  = -rrr * kv * fast_rcp(lam2 * delta);
            float C3  = -(lam1 - R) * rkv;
            float C4  = -(lam2 - R) * rkv;
            float Cn  = fmaf(Cc + C1, fast_exp2(lam1 * svc.x), -C1) * fast_exp2(lam1 * svc.y);
            float Dn  = fmaf(Dc + C2, fast_exp2(lam2 * svc.x), -C2) * fast_exp2(lam2 * svc.y);
            float An  = fmaf(Cn, C3, Dn * C4);
            Cc = Cn; Dc = Dn;
            if (tid == 512) {
                out_lds[t] = An;
                vfb_lds = fmaf(An, 1.0f - svc.z, svc.w * svc.z);   // vfb(t+1)
            }
        }
        __syncthreads();   // A: vfb(t+1) visible; h reads done
    }

    if (tid < TT / 4) ((float4*)(out + bT))[tid] = ((const float4*)out_lds)[tid];
}

extern "C" void kernel_launch(void* const* d_in, const int* in_sizes, int n_in,
                              void* d_out, int out_size, void* d_ws, size_t ws_size,
                              hipStream_t stream) {
    const float* cont  = (const float*)d_in[0];
    const int*   cat   = (const int*)  d_in[1];
    const float* lb    = (const float*)d_in[2];
    const int*   mask  = (const int*)  d_in[3];
    const float* dvec  = (const float*)d_in[4];
    const float* td    = (const float*)d_in[5];
    const float* emb   = (const float*)d_in[6];
    const float* W_ih  = (const float*)d_in[7];
    const float* W_hh  = (const float*)d_in[8];
    const float* b_ih  = (const float*)d_in[9];
    const float* b_hh  = (const float*)d_in[10];
    const float* W_out = (const float*)d_in[11];
    const float* b_out = (const float*)d_in[12];
    float* out = (float*)d_out;

    hipLaunchKernelGGL(scan_kernel, dim3(BB), dim3(BLK), 0, stream,
                       cont, cat, lb, mask, dvec, td, emb, W_ih, W_hh, b_ih, b_hh,
                       W_out, b_out, out);
}

// Round 9
// 425.114 us; speedup vs baseline: 1.1199x; 1.0009x over previous
//
#include <hip/hip_runtime.h>
#include <math.h>

#define BB 256
#define TT 512
#define LL 40
#define ED 8
#define NC 22
#define HH 64
#define BLK 576   // lanes 0-511: dots+GRU (8 lanes/unit); wave8 (512-575): eta+PK

#define L2E 1.4426950408889634f
#define S2E 2.8853900817779268f   // 2*log2(e)

__device__ __forceinline__ float fast_rcp(float x)  { return __builtin_amdgcn_rcpf(x); }
__device__ __forceinline__ float fast_exp2(float x) { return __builtin_amdgcn_exp2f(x); }

__device__ __forceinline__ float dpp_add_xor1(float x) {   // quad_perm [1,0,3,2]
    int v = __builtin_amdgcn_update_dpp(0, __float_as_int(x), 0xB1, 0xF, 0xF, true);
    return x + __int_as_float(v);
}
__device__ __forceinline__ float dpp_add_xor2(float x) {   // quad_perm [2,3,0,1]
    int v = __builtin_amdgcn_update_dpp(0, __float_as_int(x), 0x4E, 0xF, 0xF, true);
    return x + __int_as_float(v);
}
__device__ __forceinline__ float dpp_add_mirror8(float x) { // row_half_mirror (xor7 in 8-group)
    int v = __builtin_amdgcn_update_dpp(0, __float_as_int(x), 0x141, 0xF, 0xF, true);
    return x + __int_as_float(v);
}
// full sum over each 8-lane octant group (result in all 8 lanes)
__device__ __forceinline__ float red8(float x) {
    return dpp_add_mirror8(dpp_add_xor2(dpp_add_xor1(x)));
}
// sum over each 16-lane row
__device__ __forceinline__ float dpp_reduce16(float x) {
    int v;
    v = __builtin_amdgcn_update_dpp(0, __float_as_int(x), 0xB1, 0xF, 0xF, true);  x += __int_as_float(v);
    v = __builtin_amdgcn_update_dpp(0, __float_as_int(x), 0x4E, 0xF, 0xF, true);  x += __int_as_float(v);
    v = __builtin_amdgcn_update_dpp(0, __float_as_int(x), 0x141, 0xF, 0xF, true); x += __int_as_float(v);
    v = __builtin_amdgcn_update_dpp(0, __float_as_int(x), 0x140, 0xF, 0xF, true); x += __int_as_float(v);
    return x;
}

// amdgpu_waves_per_eu(3,3): clamp the scheduler's occupancy target to exactly
// what the 9-wave block needs (9 waves / 4 SIMDs = 3/EU). launch_bounds' 2nd
// arg only sets the MIN; the allocator was chasing ~10 waves/EU and spilling
// the per-lane weights to scratch (R8: VGPR_Count=48 < 39 weights), turning
// every step into a ~75 KB/CU L1 re-stream (~1100 cyc) — the R5-R8 wall.
__global__
__attribute__((amdgpu_flat_work_group_size(BLK, BLK)))
__attribute__((amdgpu_waves_per_eu(3, 3)))
void scan_kernel(
    const float* __restrict__ cont, const int* __restrict__ cat,
    const float* __restrict__ lb, const int* __restrict__ mask,
    const float* __restrict__ dvec, const float* __restrict__ td,
    const float* __restrict__ emb,
    const float* __restrict__ W_ih, const float* __restrict__ W_hh,
    const float* __restrict__ b_ih, const float* __restrict__ b_hh,
    const float* __restrict__ W_out, const float* __restrict__ b_out,
    float* __restrict__ out)
{
    const int b   = blockIdx.x;
    const int tid = threadIdx.x;

    // feat rows: 32 floats = 8 float4s: [0..7]=emb-sum, [8..29]=cont, [30]=0, [31]=0
    __shared__ __align__(128) float  feat[TT * 32];   // 64 KB
    __shared__ __align__(16)  float4 sc[TT];          // {d*L2E, (td24-d)*L2E, maskf, lb}
    __shared__ float  cclA[TT];
    __shared__ __align__(16)  float  hbuf[HH];        // h(t), plain layout
    __shared__ __align__(16)  float  out_lds[TT];
    __shared__ float vfb_lds;
    __shared__ float kb_lds;

    const size_t bT    = (size_t)b * TT;
    const int*   catb  = cat  + bT * LL;
    const float* contb = cont + bT * NC;

    // ---- roles ----
    const bool isDot = (tid < 512);
    const int  j  = tid >> 3;        // hidden unit (0..63)        [dot lanes]
    const int  s  = tid & 7;         // octant: float4 slots s, s+8(h), s+16(h)
    const int  l8 = tid - 512;       // wave8 lane (0..63)
    const int  ei = l8 & 15, ej = l8 >> 4;

    // ---- per-lane weights: 12 per gate (x-quad, h-lo-quad, h-hi-quad), prescaled ----
    float wr_[12], wz_[12], wn_[12];
    float br = 0.f, bz = 0.f, bnx = 0.f, bnh = 0.f;
    float w30r = 0.f, w30z = 0.f, w30n = 0.f;
    float wo0 = 0.f, wo1 = 0.f, wo2 = 0.f, wo3 = 0.f;
    if (isDot) {
        const int cx0 = 4 * s;
        #pragma unroll
        for (int m = 0; m < 4; ++m) {
            const int cx = cx0 + m;
            const float xr = (cx < 30) ? W_ih[j * 31 + cx]         : 0.f;
            const float xz = (cx < 30) ? W_ih[(j + 64) * 31 + cx]  : 0.f;
            const float xn = (cx < 30) ? W_ih[(j + 128) * 31 + cx] : 0.f;
            wr_[m]     = xr * L2E;
            wz_[m]     = xz * L2E;
            wn_[m]     = xn * S2E;
            wr_[4 + m] = W_hh[j * 64 + cx]              * L2E;
            wz_[4 + m] = W_hh[(j + 64) * 64 + cx]       * L2E;
            wn_[4 + m] = W_hh[(j + 128) * 64 + cx]      * S2E;
            wr_[8 + m] = W_hh[j * 64 + 32 + cx]         * L2E;
            wz_[8 + m] = W_hh[(j + 64) * 64 + 32 + cx]  * L2E;
            wn_[8 + m] = W_hh[(j + 128) * 64 + 32 + cx] * S2E;
        }
        #pragma unroll
        for (int m = 0; m < 12; ++m) {
            asm volatile("" : "+v"(wr_[m]));
            asm volatile("" : "+v"(wz_[m]));
            asm volatile("" : "+v"(wn_[m]));
        }
        br   = (b_ih[j]      + b_hh[j])      * L2E;
        bz   = (b_ih[j + 64] + b_hh[j + 64]) * L2E;
        bnx  = b_ih[j + 128] * S2E;
        bnh  = b_hh[j + 128] * S2E;
        w30r = W_ih[j * 31 + 30]         * L2E;
        w30z = W_ih[(j + 64) * 31 + 30]  * L2E;
        w30n = W_ih[(j + 128) * 31 + 30] * S2E;
    } else {
        wo0 = W_out[ej * 64 + 4 * ei + 0] * L2E;
        wo1 = W_out[ej * 64 + 4 * ei + 1] * L2E;
        wo2 = W_out[ej * 64 + 4 * ei + 2] * L2E;
        wo3 = W_out[ej * 64 + 4 * ei + 3] * L2E;
    }
    const float boL0 = b_out[0] * L2E, boL1 = b_out[1] * L2E;
    const float boL2 = b_out[2] * L2E, boL3 = b_out[3] * L2E;

    // ---- prologue: stage everything into LDS ----
    for (int i = tid; i < TT * NC; i += BLK) {          // cont -> feat[.][8..29]
        int r = i / NC, c = i - r * NC;
        feat[r * 32 + 8 + c] = contb[i];
    }
    for (int i = tid; i < TT; i += BLK) {               // pads (vfb slot excluded from dots)
        feat[i * 32 + 30] = 0.f;
        feat[i * 32 + 31] = 0.f;
    }
    for (int i = tid; i < TT * 2; i += BLK) {           // emb gather, float4-vectorized
        int r = i >> 1, qd = i & 1;                     // qd = which half of 8 emb dims
        const int* cp = catb + r * LL;
        float4 acc = make_float4(0.f, 0.f, 0.f, 0.f);
        #pragma unroll 8
        for (int l = 0; l < LL; ++l) {
            const float4 ev = *((const float4*)(emb + cp[l] * ED) + qd);
            acc.x += ev.x; acc.y += ev.y; acc.z += ev.z; acc.w += ev.w;
        }
        ((float4*)feat)[r * 8 + qd] = acc;
    }
    for (int i = tid; i < TT; i += BLK) {               // per-step scalars (exp2-prescaled)
        float d   = dvec[bT + i];
        float t24 = td[bT + i] * 24.0f;
        sc[i] = make_float4(d * L2E, (t24 - d) * L2E, (float)mask[bT + i], lb[bT + i]);
    }
    if (tid < HH) hbuf[tid] = 0.f;
    if (tid == 0) vfb_lds = 0.f;
    if (tid < 64) {                                     // Kb via ballot over cat[b][0][:]
        int cv = (tid < LL) ? catb[tid] : 0;
        unsigned long long bal = __ballot(tid < LL && cv == 5);
        float g   = (float)__popcll(bal) * 0.15f + 0.85f;
        float age = contb[2]  * 16.936469f + 58.239251f;
        float wgt = contb[21] * 30.519849f + 87.5752f;
        if (tid == 0) kb_lds = (140.0f - age) * wgt * g / 72.0f;
    }
    __syncthreads();
    {
        const float Kb = kb_lds;
        for (int i = tid; i < TT; i += BLK)
            cclA[i] = Kb * fast_rcp(fmaf(contb[i * NC + 11], 1.418099f, 1.314668f));
    }
    __syncthreads();

    // ---- persistent state ----
    float hreg = 0.f;                      // dot lanes: h_j (replicated in octant)
    float Cc = 0.f, Dc = 0.f;              // wave8 PK state
    float sr = 0.f, sz = 0.f, snx = 0.f, snh = 0.f;
    float4 svc = make_float4(0.f, 0.f, 0.f, 0.f);
    float  ccv = 0.f;

    const float4* hbuf4 = (const float4*)hbuf;

    // dots for step t: 3 conflict-free LDS float4 reads + 36 FMA + 4 octant reduces
    auto do_dots = [&](int t) {
        const float4 u0 = ((const float4*)(feat + t * 32))[s];   // x dims 4s..4s+3
        const float4 u1 = hbuf4[s];                              // h dims 4s..4s+3
        const float4 u2 = hbuf4[s + 8];                          // h dims 32+4s..
        float ra, za, nxa, nha;
        ra  = u0.x * wr_[0];
        ra  = fmaf(u0.y, wr_[1],  ra);
        ra  = fmaf(u0.z, wr_[2],  ra);
        ra  = fmaf(u0.w, wr_[3],  ra);
        ra  = fmaf(u1.x, wr_[4],  ra);
        ra  = fmaf(u1.y, wr_[5],  ra);
        ra  = fmaf(u1.z, wr_[6],  ra);
        ra  = fmaf(u1.w, wr_[7],  ra);
        ra  = fmaf(u2.x, wr_[8],  ra);
        ra  = fmaf(u2.y, wr_[9],  ra);
        ra  = fmaf(u2.z, wr_[10], ra);
        ra  = fmaf(u2.w, wr_[11], ra);
        za  = u0.x * wz_[0];
        za  = fmaf(u0.y, wz_[1],  za);
        za  = fmaf(u0.z, wz_[2],  za);
        za  = fmaf(u0.w, wz_[3],  za);
        za  = fmaf(u1.x, wz_[4],  za);
        za  = fmaf(u1.y, wz_[5],  za);
        za  = fmaf(u1.z, wz_[6],  za);
        za  = fmaf(u1.w, wz_[7],  za);
        za  = fmaf(u2.x, wz_[8],  za);
        za  = fmaf(u2.y, wz_[9],  za);
        za  = fmaf(u2.z, wz_[10], za);
        za  = fmaf(u2.w, wz_[11], za);
        nxa = u0.x * wn_[0];
        nxa = fmaf(u0.y, wn_[1],  nxa);
        nxa = fmaf(u0.z, wn_[2],  nxa);
        nxa = fmaf(u0.w, wn_[3],  nxa);
        nha = u1.x * wn_[4];
        nha = fmaf(u1.y, wn_[5],  nha);
        nha = fmaf(u1.z, wn_[6],  nha);
        nha = fmaf(u1.w, wn_[7],  nha);
        nha = fmaf(u2.x, wn_[8],  nha);
        nha = fmaf(u2.y, wn_[9],  nha);
        nha = fmaf(u2.z, wn_[10], nha);
        nha = fmaf(u2.w, wn_[11], nha);
        sr  = red8(ra);
        sz  = red8(za);
        snx = red8(nxa);
        snh = red8(nha);
    };

    if (isDot) do_dots(0);

    for (int t = 0; t < TT; ++t) {
        // ---- alpha: dot lanes GRU(t); wave8 prefetches scalars ----
        if (isDot) {
            const float vfb = vfb_lds;
            float prer = sr + br + vfb * w30r;
            float prez = sz + bz + vfb * w30z;
            float r = fast_rcp(1.0f + fast_exp2(-prer));
            float z = fast_rcp(1.0f + fast_exp2(-prez));
            float yp = snx + bnx + vfb * w30n + r * (snh + bnh);
            float n = 1.0f - 2.0f * fast_rcp(fast_exp2(yp) + 1.0f);
            hreg = fmaf(z, hreg - n, n);
            if (s == 0) hbuf[j] = hreg;
        } else {
            svc = sc[t];
            ccv = cclA[t];
        }
        __syncthreads();   // B: h(t) visible

        // ---- beta: dot lanes dots(t+1)  ||  wave8 eta+PK(t) ----
        if (isDot) {
            if (t + 1 < TT) do_dots(t + 1);
        } else {
            const float4 hv = hbuf4[ei];
            float p = hv.x * wo0;
            p = fmaf(hv.y, wo1, p);
            p = fmaf(hv.z, wo2, p);
            p = fmaf(hv.w, wo3, p);
            p = dpp_reduce16(p);
            const float e0 = __int_as_float(__builtin_amdgcn_readlane(__float_as_int(p), 0));
            const float e1 = __int_as_float(__builtin_amdgcn_readlane(__float_as_int(p), 16));
            const float e2 = __int_as_float(__builtin_amdgcn_readlane(__float_as_int(p), 32));
            const float e3 = __int_as_float(__builtin_amdgcn_readlane(__float_as_int(p), 48));

            float E1 = fast_exp2(e0 + boL0);
            float E2 = fast_exp2(e1 + boL1);
            float E3 = fast_exp2(e2 + boL2);
            float E4 = fast_exp2(e3 + boL3);
            float v1  = 33.1f * E1;
            float rv1 = fast_rcp(v1);
            float k1  = 0.0396f * ccv * E2;
            float rrr = 1000.0f * rv1;
            float v2  = 48.3f * E4;
            float R   = (-6.99f / 48.3f) * E3;
            float k2  = R * v2;
            float qq  = k1 - k2 - R * v1;
            float disc = fmaf(qq, qq, 4.0f * k1 * R * v1);
            float delta = __builtin_amdgcn_sqrtf(disc) * rv1;
            float sgm  = (k2 - k1 + R * v1) * rv1;
            float lam1 = (sgm - delta) * 0.5f;
            float lam2 = (sgm + delta) * 0.5f;
            float kv  = k2 * rv1;
            float rkv = fast_rcp(kv);
            float C1  = rrr * kv * fast_rcp(lam1 * delta);
            float C2  = -rrr * kv * fast_rcp(lam2 * delta);
            float C3  = -(lam1 - R) * rkv;
            float C4  = -(lam2 - R) * rkv;
            float Cn  = fmaf(Cc + C1, fast_exp2(lam1 * svc.x), -C1) * fast_exp2(lam1 * svc.y);
            float Dn  = fmaf(Dc + C2, fast_exp2(lam2 * svc.x), -C2) * fast_exp2(lam2 * svc.y);
            float An  = fmaf(Cn, C3, Dn * C4);
            Cc = Cn; Dc = Dn;
            if (tid == 512) {
                out_lds[t] = An;
                vfb_lds = fmaf(An, 1.0f - svc.z, svc.w * svc.z);   // vfb(t+1)
            }
        }
        __syncthreads();   // A: vfb(t+1) visible; h reads done
    }

    if (tid < TT / 4) ((float4*)(out + bT))[tid] = ((const float4*)out_lds)[tid];
}

extern "C" void kernel_launch(void* const* d_in, const int* in_sizes, int n_in,
                              void* d_out, int out_size, void* d_ws, size_t ws_size,
                              hipStream_t stream) {
    const float* cont  = (const float*)d_in[0];
    const int*   cat   = (const int*)  d_in[1];
    const float* lb    = (const float*)d_in[2];
    const int*   mask  = (const int*)  d_in[3];
    const float* dvec  = (const float*)d_in[4];
    const float* td    = (const float*)d_in[5];
    const float* emb   = (const float*)d_in[6];
    const float* W_ih  = (const float*)d_in[7];
    const float* W_hh  = (const float*)d_in[8];
    const float* b_ih  = (const float*)d_in[9];
    const float* b_hh  = (const float*)d_in[10];
    const float* W_out = (const float*)d_in[11];
    const float* b_out = (const float*)d_in[12];
    float* out = (float*)d_out;

    hipLaunchKernelGGL(scan_kernel, dim3(BB), dim3(BLK), 0, stream,
                       cont, cat, lb, mask, dvec, td, emb, W_ih, W_hh, b_ih, b_hh,
                       W_out, b_out, out);
}